// Round 2
// baseline (22326.318 us; speedup 1.0000x reference)
//
#include <hip/hip_runtime.h>
#include <hip/hip_bf16.h>
#include <cstdint>
#include <cstddef>

// LSTM encoder: B=64, T=512, D=256, UNITS=1024, gates G=4096 (i|f|g|o).
// z_t = x_t @ W + h_{t-1} @ U + b -> gates -> c,h.  Fused K = 1024(U) + 256(W).
// Persistent: 256 WGs, WG owns 4 units (16 gate cols). Per-step grid barrier =
// padded per-WG flag slots (parallel stores + distributed acquire-poll), NOT a
// contended atomic counter (R1: 256 serialized cross-XCD RMWs ~= 38us/step).
// Weights live in LDS (40KB/WG, staged once). x@W MFMAs run in the wait window.

#define NWG    256
#define KSTEPS 40          // 1280 / 32 MFMA k-steps
#define NITER  20          // fused K loop iterations (2 MFMAs each): 16 U + 4 W
#define SEQ_N  33554432    // 64*512*1024

typedef __attribute__((ext_vector_type(8))) short short8;
typedef __attribute__((ext_vector_type(4))) float floatx4;

static __device__ __forceinline__ short f2bf(float f) {
  __hip_bfloat16 h = __float2bfloat16(f);
  return *reinterpret_cast<short*>(&h);
}
static __device__ __forceinline__ float sigm(float x) { return 1.f / (1.f + __expf(-x)); }
static __device__ __forceinline__ float tanh_fast(float x) {
  float xc = fminf(fmaxf(x, -15.f), 15.f);
  float e  = __expf(2.f * xc);
  return (e - 1.f) / (e + 1.f);
}

// ---- prep: pack [U;W] into per-WG MFMA B-fragment order, bf16 ----
// lane L of iter kk reads upack[wg*20480 + (kk*64 + L)*8 + j]
//   == Bsrc[k = kk*32 + (L>>4)*8 + j][gatecol = (n>>2)*1024 + wg*4 + (n&3)], n=L&15
__global__ void pack_weights(const float* __restrict__ W, const float* __restrict__ U,
                             short* __restrict__ upack) {
  int idx  = blockIdx.x * 256 + threadIdx.x;   // 0 .. 256*40*64-1 exact
  int lane = idx & 63;
  int kk   = (idx >> 6) % KSTEPS;
  int wg   = idx / (KSTEPS * 64);
  int quad = lane >> 4, n = lane & 15;
  int col  = (n >> 2) * 1024 + wg * 4 + (n & 3);
  int k0   = kk * 32 + quad * 8;
  short8 v;
#pragma unroll
  for (int j = 0; j < 8; ++j) {
    int k = k0 + j;
    float f = (k < 1024) ? U[(size_t)k * 4096 + col] : W[(size_t)(k - 1024) * 4096 + col];
    v[j] = f2bf(f);
  }
  *reinterpret_cast<short8*>(upack + (size_t)idx * 8) = v;
}

__global__ void convert_x(const float* __restrict__ x, short* __restrict__ xbf) {
  int idx = blockIdx.x * 256 + threadIdx.x;    // 8 elems each, 64*512*256/8 exact
  const float* xp = x + (size_t)idx * 8;
  short8 v;
#pragma unroll
  for (int j = 0; j < 8; ++j) v[j] = f2bf(xp[j]);
  *reinterpret_cast<short8*>(xbf + (size_t)idx * 8) = v;
}

// ---- persistent stepper ----
__global__ __launch_bounds__(256, 1) void lstm_persist(
    const short* __restrict__ xbf,    // [64][512][256] bf16
    const short* __restrict__ upack,  // packed B frags, 20480 shorts per WG
    const float* __restrict__ bias,   // [4096] f32
    short* __restrict__ hbuf,         // [2][64][1024] bf16 (zeroed)
    int*   __restrict__ arrive,       // [256*32] ints, 128B-padded slots (zeroed)
    float* __restrict__ out)          // seq | h_last | c_last
{
  __shared__ short wlds[20480];       // 40KB weight fragments
  __shared__ float zlds[64 * 17];

  const int wg   = blockIdx.x;
  const int tid  = threadIdx.x;
  const int wave = tid >> 6;
  const int lane = tid & 63;
  const int quad = lane >> 4;
  const int l15  = lane & 15;
  const int arow = wave * 16 + l15;          // A-operand batch row (m = lane&15)
  const int eb   = tid >> 2;                 // elementwise batch
  const int ej   = tid & 3;                  // elementwise unit-in-wg
  const int unit = wg * 4 + ej;
  const float bi = bias[unit];
  const float bf = bias[1024 + unit];
  const float bg = bias[2048 + unit];
  const float bo = bias[3072 + unit];
  float creg = 0.f;

  // stage this WG's weights into LDS (40960B, 16B x 2560 chunks)
  {
    const short* src = upack + (size_t)wg * 20480;
#pragma unroll
    for (int i = 0; i < 10; ++i) {
      int idx = i * 256 + tid;
      *reinterpret_cast<short8*>(wlds + idx * 8) =
          *reinterpret_cast<const short8*>(src + idx * 8);
    }
  }
  __syncthreads();

  const short* xrow   = xbf + (size_t)arow * 512 * 256 + quad * 8;
  const short* wlane  = wlds + lane * 8;
  int* myslot = arrive + tid * 32;

  // x@W part for step t (K rows 1024..1279 = iters 16..19)
  auto compute_x = [&](int t, floatx4& a0o, floatx4& a1o) {
    floatx4 a0 = {0.f, 0.f, 0.f, 0.f};
    floatx4 a1 = {0.f, 0.f, 0.f, 0.f};
    const short* xp = xrow + t * 256;
    const short* wp = wlane + 16 * 1024;
#pragma unroll
    for (int it = 0; it < 4; ++it) {
      short8 av0 = *reinterpret_cast<const short8*>(xp);
      short8 bv0 = *reinterpret_cast<const short8*>(wp);
      short8 av1 = *reinterpret_cast<const short8*>(xp + 32);
      short8 bv1 = *reinterpret_cast<const short8*>(wp + 512);
      xp += 64; wp += 1024;
      a0 = __builtin_amdgcn_mfma_f32_16x16x32_bf16(av0, bv0, a0, 0, 0, 0);
      a1 = __builtin_amdgcn_mfma_f32_16x16x32_bf16(av1, bv1, a1, 0, 0, 0);
    }
    a0o = a0; a1o = a1;
  };

  floatx4 xa0, xa1;
  compute_x(0, xa0, xa1);

  for (int t = 0; t < 512; ++t) {
    const short* hsrc = hbuf + ((t & 1) << 16);
    short*       hdst = hbuf + (((t + 1) & 1) << 16);

    floatx4 acc0 = xa0, acc1 = xa1;
    {
      const short* ap = hsrc + arow * 1024 + quad * 8;
      const short* wp = wlane;
#pragma unroll 4
      for (int it = 0; it < 16; ++it) {      // h@U: K 0..1023
        short8 a0 = *reinterpret_cast<const short8*>(ap);
        short8 b0 = *reinterpret_cast<const short8*>(wp);
        short8 a1 = *reinterpret_cast<const short8*>(ap + 32);
        short8 b1 = *reinterpret_cast<const short8*>(wp + 512);
        ap += 64; wp += 1024;
        acc0 = __builtin_amdgcn_mfma_f32_16x16x32_bf16(a0, b0, acc0, 0, 0, 0);
        acc1 = __builtin_amdgcn_mfma_f32_16x16x32_bf16(a1, b1, acc1, 0, 0, 0);
      }
    }
    acc0 = acc0 + acc1;

    // C layout: col = lane&15, row = quad*4 + r  -> zlds[batchrow][gatecol]
#pragma unroll
    for (int r = 0; r < 4; ++r)
      zlds[(wave * 16 + quad * 4 + r) * 17 + l15] = acc0[r];
    __syncthreads();

    float zi = zlds[eb * 17 + 0  + ej] + bi;
    float zf = zlds[eb * 17 + 4  + ej] + bf;
    float zg = zlds[eb * 17 + 8  + ej] + bg;
    float zo = zlds[eb * 17 + 12 + ej] + bo;
    float ig = sigm(zi), fg = sigm(zf), gg = tanh_fast(zg), og = sigm(zo);
    float cn = fg * creg + ig * gg;
    creg = cn;
    float hn = og * tanh_fast(cn);

    hdst[eb * 1024 + unit] = f2bf(hn);
    out[((size_t)eb * 512 + t) * 1024 + unit] = hn;
    if (t == 511) {
      out[(size_t)SEQ_N + eb * 1024 + unit] = hn;                 // h_last
      out[(size_t)SEQ_N + 65536 + eb * 1024 + unit] = cn;         // c_last
    }

    if (t < 511) {
      __threadfence();               // own h stores -> device scope
      __syncthreads();               // all threads' stores fenced
      if (tid == 0)
        __hip_atomic_store(&arrive[wg * 32], t + 1, __ATOMIC_RELEASE,
                           __HIP_MEMORY_SCOPE_AGENT);
      compute_x(t + 1, xa0, xa1);    // hide x@W in the wait window
      while (__hip_atomic_load(myslot, __ATOMIC_ACQUIRE,
                               __HIP_MEMORY_SCOPE_AGENT) < t + 1) {
        __builtin_amdgcn_s_sleep(1);
      }
      __syncthreads();               // all 256 slots confirmed by their pollers
    }
  }
}

extern "C" void kernel_launch(void* const* d_in, const int* in_sizes, int n_in,
                              void* d_out, int out_size, void* d_ws, size_t ws_size,
                              hipStream_t stream) {
  const float* x    = (const float*)d_in[0];
  const float* W    = (const float*)d_in[1];
  const float* U    = (const float*)d_in[2];
  const float* bias = (const float*)d_in[3];
  float* out = (float*)d_out;
  char* ws = (char*)d_ws;

  short* upack  = (short*)ws;                      // 10,485,760 B
  short* xbf    = (short*)(ws + 10485760);         // 16,777,216 B
  short* hbuf   = (short*)(ws + 27262976);         //    262,144 B (2 buffers)
  int*   arrive = (int*)  (ws + 27525120);         //     32,768 B padded slots
  (void)in_sizes; (void)n_in; (void)out_size; (void)ws_size;

  hipMemsetAsync(hbuf, 0, 262144 + 32768, stream); // h0 = 0, arrival slots = 0
  pack_weights<<<2560, 256, 0, stream>>>(W, U, upack);
  convert_x<<<4096, 256, 0, stream>>>(x, xbf);
  lstm_persist<<<NWG, 256, 0, stream>>>(xbf, upack, bias, hbuf, arrive, out);
}

// Round 3
// 5175.707 us; speedup vs baseline: 4.3137x; 4.3137x over previous
//
#include <hip/hip_runtime.h>
#include <hip/hip_bf16.h>
#include <cstdint>
#include <cstddef>

// LSTM encoder: B=64, T=512, D=256, UNITS=1024, gates G=4096 (i|f|g|o).
// z_t = x_t @ W + h_{t-1} @ U + b -> gates -> c,h.  Fused K = 1024(U) + 256(W).
// Persistent: 256 WGs, WG owns 4 units. R1/R2 lesson: __threadfence (agent
// release/acquire) emits buffer_wbl2/buffer_inv = full L2 flush per step
// (~40us). R3: ALL cross-WG traffic via RELAXED agent-scope atomics (sc1
// bypass per-access, no cache maintenance). Ordering: s_waitcnt(0) + flag.

#define NWG    256
#define KSTEPS 40
#define SEQ_N  33554432    // 64*512*1024

typedef __attribute__((ext_vector_type(8))) short short8;
typedef __attribute__((ext_vector_type(4))) float floatx4;

union frag_cast { unsigned long long u[2]; short8 v; };

static __device__ __forceinline__ short f2bf(float f) {
  __hip_bfloat16 h = __float2bfloat16(f);
  return *reinterpret_cast<short*>(&h);
}
static __device__ __forceinline__ float sigm(float x) { return 1.f / (1.f + __expf(-x)); }
static __device__ __forceinline__ float tanh_fast(float x) {
  float xc = fminf(fmaxf(x, -15.f), 15.f);
  float e  = __expf(2.f * xc);
  return (e - 1.f) / (e + 1.f);
}

// ---- prep: pack [U;W] into per-WG MFMA B-fragment order, bf16 ----
__global__ void pack_weights(const float* __restrict__ W, const float* __restrict__ U,
                             short* __restrict__ upack) {
  int idx  = blockIdx.x * 256 + threadIdx.x;   // 0 .. 256*40*64-1
  int lane = idx & 63;
  int kk   = (idx >> 6) % KSTEPS;
  int wg   = idx / (KSTEPS * 64);
  int quad = lane >> 4, n = lane & 15;
  int col  = (n >> 2) * 1024 + wg * 4 + (n & 3);
  int k0   = kk * 32 + quad * 8;
  short8 v;
#pragma unroll
  for (int j = 0; j < 8; ++j) {
    int k = k0 + j;
    float f = (k < 1024) ? U[(size_t)k * 4096 + col] : W[(size_t)(k - 1024) * 4096 + col];
    v[j] = f2bf(f);
  }
  *reinterpret_cast<short8*>(upack + (size_t)idx * 8) = v;
}

__global__ void convert_x(const float* __restrict__ x, short* __restrict__ xbf) {
  int idx = blockIdx.x * 256 + threadIdx.x;
  const float* xp = x + (size_t)idx * 8;
  short8 v;
#pragma unroll
  for (int j = 0; j < 8; ++j) v[j] = f2bf(xp[j]);
  *reinterpret_cast<short8*>(xbf + (size_t)idx * 8) = v;
}

// zero h0 + flags AT THE COHERENCE POINT (bypassing stores), so the
// persistent kernel's bypassing loads can't see stale poison.
__global__ void init_state(unsigned int* __restrict__ hbuf32,
                           int* __restrict__ arrive) {
  int idx = blockIdx.x * 256 + threadIdx.x;    // 288 blocks
  if (idx < 65536)
    __hip_atomic_store(&hbuf32[idx], 0u, __ATOMIC_RELAXED, __HIP_MEMORY_SCOPE_AGENT);
  else
    __hip_atomic_store(&arrive[idx - 65536], 0, __ATOMIC_RELAXED, __HIP_MEMORY_SCOPE_AGENT);
}

// ---- persistent stepper ----
__global__ __launch_bounds__(256, 1) void lstm_persist(
    const short* __restrict__ xbf,            // [64][512][256] bf16
    const short* __restrict__ upack,          // packed B frags, 20480 shorts/WG
    const float* __restrict__ bias,           // [4096] f32
    unsigned long long* __restrict__ hbuf64,  // [2][64][1024] bf16 as ull
    int* __restrict__ arrive,                 // [256*32] padded flag slots
    float* __restrict__ out)
{
  __shared__ short wlds[20480];       // 40KB weight fragments
  __shared__ float zlds[64 * 17];

  const int wg   = blockIdx.x;
  const int tid  = threadIdx.x;
  const int wave = tid >> 6;
  const int lane = tid & 63;
  const int quad = lane >> 4;
  const int l15  = lane & 15;
  const int arow = wave * 16 + l15;          // A-operand batch row
  const int eb   = tid >> 2;                 // elementwise batch
  const int ej   = tid & 3;                  // elementwise unit-in-wg
  const int unit = wg * 4 + ej;
  const float bi = bias[unit];
  const float bf = bias[1024 + unit];
  const float bg = bias[2048 + unit];
  const float bo = bias[3072 + unit];
  float creg = 0.f;

  unsigned int* hbuf32 = reinterpret_cast<unsigned int*>(hbuf64);

  // stage this WG's weights into LDS
  {
    const short* src = upack + (size_t)wg * 20480;
#pragma unroll
    for (int i = 0; i < 10; ++i) {
      int idx = i * 256 + tid;
      *reinterpret_cast<short8*>(wlds + idx * 8) =
          *reinterpret_cast<const short8*>(src + idx * 8);
    }
  }
  __syncthreads();

  const short* xrow  = xbf + (size_t)arow * 512 * 256 + quad * 8;
  const short* wlane = wlds + lane * 8;
  int* myslot = arrive + tid * 32;

  auto compute_x = [&](int t, floatx4& a0o, floatx4& a1o) {
    floatx4 a0 = {0.f, 0.f, 0.f, 0.f};
    floatx4 a1 = {0.f, 0.f, 0.f, 0.f};
    const short* xp = xrow + t * 256;
    const short* wp = wlane + 16 * 1024;
#pragma unroll
    for (int it = 0; it < 4; ++it) {
      short8 av0 = *reinterpret_cast<const short8*>(xp);
      short8 bv0 = *reinterpret_cast<const short8*>(wp);
      short8 av1 = *reinterpret_cast<const short8*>(xp + 32);
      short8 bv1 = *reinterpret_cast<const short8*>(wp + 512);
      xp += 64; wp += 1024;
      a0 = __builtin_amdgcn_mfma_f32_16x16x32_bf16(av0, bv0, a0, 0, 0, 0);
      a1 = __builtin_amdgcn_mfma_f32_16x16x32_bf16(av1, bv1, a1, 0, 0, 0);
    }
    a0o = a0; a1o = a1;
  };

  floatx4 xa0, xa1;
  compute_x(0, xa0, xa1);

  for (int t = 0; t < 512; ++t) {
    const unsigned long long* hsrc = hbuf64 + ((size_t)(t & 1) << 14);       // 16384 ull
    unsigned int*             hdst = hbuf32 + ((size_t)((t + 1) & 1) << 15); // 32768 u32

    floatx4 acc0 = xa0, acc1 = xa1;
    {
      const unsigned long long* ap = hsrc + arow * 256 + quad * 2;
      const short* wp = wlane;
#pragma unroll 4
      for (int it = 0; it < 16; ++it) {      // h@U: K 0..1023
        frag_cast fa0, fa1;
        fa0.u[0] = __hip_atomic_load(ap + 0, __ATOMIC_RELAXED, __HIP_MEMORY_SCOPE_AGENT);
        fa0.u[1] = __hip_atomic_load(ap + 1, __ATOMIC_RELAXED, __HIP_MEMORY_SCOPE_AGENT);
        fa1.u[0] = __hip_atomic_load(ap + 8, __ATOMIC_RELAXED, __HIP_MEMORY_SCOPE_AGENT);
        fa1.u[1] = __hip_atomic_load(ap + 9, __ATOMIC_RELAXED, __HIP_MEMORY_SCOPE_AGENT);
        short8 b0 = *reinterpret_cast<const short8*>(wp);
        short8 b1 = *reinterpret_cast<const short8*>(wp + 512);
        ap += 16; wp += 1024;
        acc0 = __builtin_amdgcn_mfma_f32_16x16x32_bf16(fa0.v, b0, acc0, 0, 0, 0);
        acc1 = __builtin_amdgcn_mfma_f32_16x16x32_bf16(fa1.v, b1, acc1, 0, 0, 0);
      }
    }
    acc0 = acc0 + acc1;

    // C layout: col = lane&15, row = quad*4 + r
#pragma unroll
    for (int r = 0; r < 4; ++r)
      zlds[(wave * 16 + quad * 4 + r) * 17 + l15] = acc0[r];
    __syncthreads();

    float zi = zlds[eb * 17 + 0  + ej] + bi;
    float zf = zlds[eb * 17 + 4  + ej] + bf;
    float zg = zlds[eb * 17 + 8  + ej] + bg;
    float zo = zlds[eb * 17 + 12 + ej] + bo;
    float ig = sigm(zi), fg = sigm(zf), gg = tanh_fast(zg), og = sigm(zo);
    float cn = fg * creg + ig * gg;
    creg = cn;
    float hn = og * tanh_fast(cn);

    // pack 2 bf16 per uint via lane-pair shuffle, store bypassing (relaxed agent)
    float hn_nb = __shfl_xor(hn, 1);
    if ((ej & 1) == 0) {
      unsigned int val = (unsigned int)(unsigned short)f2bf(hn) |
                         ((unsigned int)(unsigned short)f2bf(hn_nb) << 16);
      __hip_atomic_store(&hdst[eb * 512 + wg * 2 + (ej >> 1)], val,
                         __ATOMIC_RELAXED, __HIP_MEMORY_SCOPE_AGENT);
    }
    out[((size_t)eb * 512 + t) * 1024 + unit] = hn;
    if (t == 511) {
      out[(size_t)SEQ_N + eb * 1024 + unit] = hn;                 // h_last
      out[(size_t)SEQ_N + 65536 + eb * 1024 + unit] = cn;         // c_last
    }

    if (t < 511) {
      __atomic_signal_fence(__ATOMIC_SEQ_CST);
      __builtin_amdgcn_s_waitcnt(0);   // h stores at coherence point
      __atomic_signal_fence(__ATOMIC_SEQ_CST);
      __syncthreads();                 // whole WG's h stores done
      if (tid == 0)
        __hip_atomic_store(&arrive[wg * 32], t + 1, __ATOMIC_RELAXED,
                           __HIP_MEMORY_SCOPE_AGENT);
      compute_x(t + 1, xa0, xa1);      // hide x@W in the wait window
      while (__hip_atomic_load(myslot, __ATOMIC_RELAXED,
                               __HIP_MEMORY_SCOPE_AGENT) < t + 1) {
        __builtin_amdgcn_s_sleep(1);
      }
      __atomic_signal_fence(__ATOMIC_SEQ_CST);
      __syncthreads();                 // all 256 flags confirmed
    }
  }
}

extern "C" void kernel_launch(void* const* d_in, const int* in_sizes, int n_in,
                              void* d_out, int out_size, void* d_ws, size_t ws_size,
                              hipStream_t stream) {
  const float* x    = (const float*)d_in[0];
  const float* W    = (const float*)d_in[1];
  const float* U    = (const float*)d_in[2];
  const float* bias = (const float*)d_in[3];
  float* out = (float*)d_out;
  char* ws = (char*)d_ws;

  short* upack = (short*)ws;                      // 10,485,760 B
  short* xbf   = (short*)(ws + 10485760);         // 16,777,216 B
  unsigned long long* hbuf = (unsigned long long*)(ws + 27262976); // 262,144 B
  int* arrive  = (int*)(ws + 27525120);           //     32,768 B
  (void)in_sizes; (void)n_in; (void)out_size; (void)ws_size;

  init_state<<<288, 256, 0, stream>>>((unsigned int*)hbuf, arrive);
  pack_weights<<<2560, 256, 0, stream>>>(W, U, upack);
  convert_x<<<4096, 256, 0, stream>>>(x, xbf);
  lstm_persist<<<NWG, 256, 0, stream>>>(xbf, upack, bias, hbuf, arrive, out);
}